// Round 7
// baseline (438.994 us; speedup 1.0000x reference)
//
#include <hip/hip_runtime.h>

// MultilayeredNetwork: 8-step recurrent sparse net, CSR-per-call v5 (DETERMINISTIC build).
// Stable 2-digit counting sort of edges: digit1 = bucket (row>>9, 196 bins),
// digit2 = local row (row&511). Every edge's final position is a pure function of
// the input (per-chunk count matrices + exclusive scans + in-wave equality-ballot
// ranking) -> packed[] holds each row's edges in ORIGINAL EDGE ORDER.
// => k_layer accumulates in plain float (matches reference's summation order),
// bitwise-deterministic across graph replays. No fixed-point needed.
//   per t: plane[t][n][b] = act(sum_e val*state[col][b]) [+ inject, clamp]
//   final: planes[t][n][b] -> out[b][n][t]

#define N_NEURONS 100000
#define NNZ_CNT   3200000
#define N_SENSORY 5000
#define BATCH     16
#define T_LAYERS  8
#define THRESH    0.01f
#define STEEP     5.0f

#define NB (N_NEURONS * BATCH)
#define NT (N_NEURONS * T_LAYERS)
#define ST (N_SENSORY * T_LAYERS)

#define LBITS    9
#define BROWS    (1 << LBITS)                          /* 512 rows per bucket */
#define NBUCKET  ((N_NEURONS + BROWS - 1) / BROWS)     /* 196 */
#define EPC      512                                   /* edges per chunk */
#define NCHUNK_A (NNZ_CNT / EPC)                       /* 6250 (exact) */
#define MAXW     34                                    /* max chunks per bucket slab (mean 32, +8 sigma) */
#define NCHUNK_B (NBUCKET * MAXW)                      /* 6664 */

#define FXSCALE   17592186044416.0f        /* fallback path only */
#define FXINV     (1.0 / 17592186044416.0)

__device__ __forceinline__ float thresh_clamp_inp(float u) {
    u = (u >= THRESH) ? u : 0.0f;
    return fminf(u, 1.0f);
}
__device__ __forceinline__ float activate(float y) {
    y = (y >= THRESH) ? y : 0.0f;
    return tanhf(STEEP * y);
}

// ---------------- deterministic 2-digit counting sort ----------------

// count digit-1: per 512-edge chunk, 196-bin histogram -> M[chunk][bucket]
__global__ void __launch_bounds__(256) k_countA(const int* __restrict__ rows,
                                                int* __restrict__ M) {
    __shared__ int cnt[4][NBUCKET];
    int wv = threadIdx.x >> 6, ln = threadIdx.x & 63;
    int chunk = blockIdx.x * 4 + wv;
    for (int j = ln; j < NBUCKET; j += 64) cnt[wv][j] = 0;
    __syncthreads();
    if (chunk < NCHUNK_A) {
        int base = chunk * EPC;
        #pragma unroll
        for (int it = 0; it < 8; ++it)
            atomicAdd(&cnt[wv][rows[base + it * 64 + ln] >> LBITS], 1);
    }
    __syncthreads();
    if (chunk < NCHUNK_A)
        for (int j = ln; j < NBUCKET; j += 64) M[chunk * NBUCKET + j] = cnt[wv][j];
}

// column-wise exclusive scan of M over chunks (per bucket); totals -> btotal
__global__ void __launch_bounds__(1024) k_scanA(int* __restrict__ M,
                                                int* __restrict__ btotal) {
    __shared__ int lds[1024];
    int j = blockIdx.x, tid = threadIdx.x;
    int running = 0;
    for (int c0 = 0; c0 < NCHUNK_A; c0 += 1024) {
        int c = c0 + tid;
        int v = (c < NCHUNK_A) ? M[c * NBUCKET + j] : 0;
        lds[tid] = v;
        __syncthreads();
        for (int off = 1; off < 1024; off <<= 1) {
            int add = (tid >= off) ? lds[tid - off] : 0;
            __syncthreads();
            lds[tid] += add;
            __syncthreads();
        }
        if (c < NCHUNK_A) M[c * NBUCKET + j] = running + lds[tid] - v;  // exclusive
        int total = lds[1023];
        __syncthreads();
        running += total;
    }
    if (tid == 0) btotal[j] = running;
}

// tiny scan: bucket totals -> bucket bases
__global__ void k_bscan(const int* __restrict__ btotal, int* __restrict__ bbase,
                        int* __restrict__ row_ptr) {
    __shared__ int lds[256];
    int tid = threadIdx.x;
    int v = (tid < NBUCKET) ? btotal[tid] : 0;
    lds[tid] = v;
    __syncthreads();
    for (int off = 1; off < 256; off <<= 1) {
        int add = (tid >= off) ? lds[tid - off] : 0;
        __syncthreads();
        lds[tid] += add;
        __syncthreads();
    }
    if (tid < NBUCKET) bbase[tid] = lds[tid] - v;
    if (tid == 0) { bbase[NBUCKET] = NNZ_CNT; row_ptr[N_NEURONS] = NNZ_CNT; }
}

// stable scatter digit-1: chunk-order + in-wave ballot-rank -> slab (edge order preserved
// within each bucket). lo word packs (col << 9) | (row & 511).
__global__ void __launch_bounds__(256) k_placeA(const int* __restrict__ rows,
                                                const int* __restrict__ cols,
                                                const float* __restrict__ vals,
                                                const int* __restrict__ M,
                                                const int* __restrict__ bbase,
                                                int2* __restrict__ slab) {
    __shared__ int cur[4][NBUCKET];
    int wv = threadIdx.x >> 6, ln = threadIdx.x & 63;
    int chunk = blockIdx.x * 4 + wv;
    bool cv = chunk < NCHUNK_A;
    if (cv)
        for (int j = ln; j < NBUCKET; j += 64)
            cur[wv][j] = bbase[j] + M[chunk * NBUCKET + j];
    __syncthreads();
    if (cv) {
        int base = chunk * EPC;
        #pragma unroll
        for (int it = 0; it < 8; ++it) {
            int e = base + it * 64 + ln;
            int r = rows[e];
            int key = r >> LBITS;                       // 8-bit key
            unsigned long long mask = ~0ull;
            #pragma unroll
            for (int bit = 0; bit < 8; ++bit) {
                unsigned long long bb = __ballot((key >> bit) & 1);
                mask &= ((key >> bit) & 1) ? bb : ~bb;  // lanes with identical key
            }
            int rank = __popcll(mask & ((1ull << ln) - 1ull));
            int cnt  = __popcll(mask);
            int leader = __ffsll((unsigned long long)mask) - 1;
            int bpos = 0;
            if (rank == 0) bpos = atomicAdd(&cur[wv][key], cnt);  // one updater/key/iter
            bpos = __shfl(bpos, leader, 64);
            slab[bpos + rank] = make_int2((cols[e] << LBITS) | (r & (BROWS - 1)),
                                          __float_as_int(vals[e]));
        }
    }
}

// count digit-2: per bucket-chunk (512 slab edges), 512-bin local-row histogram
__global__ void __launch_bounds__(256) k_countB(const int* __restrict__ bbase,
                                                const int2* __restrict__ slab,
                                                int* __restrict__ C2) {
    __shared__ int cnt[BROWS];
    int j = blockIdx.x / MAXW, w = blockIdx.x % MAXW;
    int P0 = bbase[j], P1 = bbase[j + 1];
    int s0 = P0 + w * EPC;
    for (int lr = threadIdx.x; lr < BROWS; lr += 256) cnt[lr] = 0;
    __syncthreads();
    if (s0 < P1) {
        int send = min(s0 + EPC, P1);
        for (int s = s0 + threadIdx.x; s < send; s += 256)
            atomicAdd(&cnt[slab[s].x & (BROWS - 1)], 1);
    }
    __syncthreads();
    for (int lr = threadIdx.x; lr < BROWS; lr += 256)
        C2[blockIdx.x * BROWS + lr] = cnt[lr];
}

// per bucket: row bases (-> row_ptr) + per-chunk exclusive offsets (C2 in place)
__global__ void __launch_bounds__(512) k_scanB(const int* __restrict__ bbase,
                                               int* __restrict__ C2,
                                               int* __restrict__ row_ptr) {
    __shared__ int scn[BROWS];
    int j = blockIdx.x, lr = threadIdx.x;
    int P0 = bbase[j];
    int t = 0;
    for (int w = 0; w < MAXW; ++w) t += C2[(j * MAXW + w) * BROWS + lr];
    scn[lr] = t;
    __syncthreads();
    for (int off = 1; off < BROWS; off <<= 1) {
        int add = (lr >= off) ? scn[lr - off] : 0;
        __syncthreads();
        scn[lr] += add;
        __syncthreads();
    }
    int rowbase = P0 + scn[lr] - t;    // exclusive
    int r = j * BROWS + lr;
    if (r < N_NEURONS) row_ptr[r] = rowbase;
    int runw = rowbase;
    for (int w = 0; w < MAXW; ++w) {
        int idx = (j * MAXW + w) * BROWS + lr;
        int c = C2[idx];
        C2[idx] = runw;
        runw += c;
    }
}

// stable scatter digit-2: slab-order + in-wave ballot-rank -> final CSR positions
__global__ void __launch_bounds__(256) k_placeB(const int* __restrict__ bbase,
                                                const int2* __restrict__ slab,
                                                const int* __restrict__ C2,
                                                int2* __restrict__ packed) {
    __shared__ int cur[4][BROWS];
    int wv = threadIdx.x >> 6, ln = threadIdx.x & 63;
    int g = blockIdx.x * 4 + wv;
    bool gv = g < NCHUNK_B;
    int j = gv ? g / MAXW : 0, w = gv ? g % MAXW : 0;
    int P0 = bbase[j], P1 = bbase[j + 1];
    int s0 = P0 + w * EPC;
    gv = gv && (s0 < P1);
    if (gv)
        for (int lr = ln; lr < BROWS; lr += 64) cur[wv][lr] = C2[g * BROWS + lr];
    __syncthreads();
    if (gv) {
        int send = min(s0 + EPC, P1);
        #pragma unroll
        for (int it = 0; it < 8; ++it) {
            int s = s0 + it * 64 + ln;
            bool act = s < send;
            unsigned long long amask = __ballot(act);
            if (act) {
                int2 pe = slab[s];
                int key = pe.x & (BROWS - 1);           // 9-bit key
                unsigned long long mask = amask;
                #pragma unroll
                for (int bit = 0; bit < LBITS; ++bit) {
                    unsigned long long bb = __ballot((key >> bit) & 1);
                    mask &= ((key >> bit) & 1) ? bb : ~bb;
                }
                int rank = __popcll(mask & ((1ull << ln) - 1ull));
                int cnt  = __popcll(mask);
                int leader = __ffsll((unsigned long long)mask) - 1;
                int bpos = 0;
                if (rank == 0) bpos = atomicAdd(&cur[wv][key], cnt);
                bpos = __shfl(bpos, leader, 64);
                packed[bpos + rank] = make_int2(pe.x >> LBITS, pe.y);
            }
        }
    }
}

// ---------------- state0 ----------------
__global__ void k_init(const float* __restrict__ inp, float* __restrict__ state0) {
    int i = blockIdx.x * blockDim.x + threadIdx.x;
    if (i >= NB) return;
    int n = i >> 4, b = i & 15;
    float v = 0.0f;
    if (n < N_SENSORY) v = thresh_clamp_inp(inp[b * ST + n * T_LAYERS + 0]);
    state0[i] = v;
}

// ---------------- fused per-layer SpMM + activation (plain float) ----------------
// 16 lanes per row (one per batch); edges in original order -> matches ref summation.
__global__ void __launch_bounds__(256) k_layer(const int* __restrict__ row_ptr,
                                               const int2* __restrict__ packed,
                                               const float* __restrict__ state_in,
                                               const float* __restrict__ inp,
                                               float* __restrict__ plane_out,
                                               int t) {
    int tid = blockIdx.x * blockDim.x + threadIdx.x;
    int r = tid >> 4, b = tid & 15;
    if (r >= N_NEURONS) return;
    int s = row_ptr[r], e = row_ptr[r + 1];
    float acc = 0.0f;
    for (int base = s; base < e; base += 16) {
        int idx = base + b;
        int2 pe = (idx < e) ? packed[idx] : make_int2(0, 0);   // val=0 pad: exact no-op
        #pragma unroll
        for (int jj = 0; jj < 16; ++jj) {
            int   c = __shfl(pe.x, jj, 16);
            float v = __int_as_float(__shfl(pe.y, jj, 16));
            acc = fmaf(v, state_in[c * BATCH + b], acc);        // coalesced 64B gather
        }
    }
    float a = activate(acc);
    if (t < T_LAYERS - 1) {
        if (r < N_SENSORY) a += thresh_clamp_inp(inp[b * ST + r * T_LAYERS + (t + 1)]);
        a = fminf(a, 1.0f);
    }
    plane_out[r * BATCH + b] = a;
}

// ---------------- planes[t][n][b] -> out[b][n][t] ----------------
__global__ void k_out(const float* __restrict__ planes, float* __restrict__ out) {
    int i = blockIdx.x * blockDim.x + threadIdx.x;
    if (i >= NB) return;
    int n = i >> 4, b = i & 15;
    float4 o0, o1;
    o0.x = planes[0 * NB + i]; o0.y = planes[1 * NB + i];
    o0.z = planes[2 * NB + i]; o0.w = planes[3 * NB + i];
    o1.x = planes[4 * NB + i]; o1.y = planes[5 * NB + i];
    o1.z = planes[6 * NB + i]; o1.w = planes[7 * NB + i];
    float4* dst = (float4*)&out[b * NT + n * T_LAYERS];
    dst[0] = o0; dst[1] = o1;
}

// ---------------- fallback (atomic fixed-point path, 19.2 MB ws) ----------------
__global__ void k2_init(const float* __restrict__ inp, float* __restrict__ state,
                        long long* __restrict__ acc) {
    int stride = gridDim.x * blockDim.x;
    for (int i = blockIdx.x * blockDim.x + threadIdx.x; i < NB; i += stride) {
        int n = i >> 4, b = i & 15;
        float v = 0.0f;
        if (n < N_SENSORY) v = thresh_clamp_inp(inp[b * ST + n * T_LAYERS + 0]);
        state[i] = v;
        acc[i]   = 0LL;
    }
}
__global__ void __launch_bounds__(256) k2_spmm(const float* __restrict__ vals,
                                               const int* __restrict__ rows,
                                               const int* __restrict__ cols,
                                               const float* __restrict__ state,
                                               long long* acc) {
    int tid = blockIdx.x * blockDim.x + threadIdx.x;
    int b = tid & 15;
    int e = tid >> 4;
    int estride = (gridDim.x * blockDim.x) >> 4;
    for (; e < NNZ_CNT; e += estride) {
        float xv = state[cols[e] * BATCH + b];
        long long fx = llrintf(vals[e] * xv * FXSCALE);
        if (fx != 0LL)
            atomicAdd((unsigned long long*)&acc[rows[e] * BATCH + b], (unsigned long long)fx);
    }
}
__global__ void k2_act_inject(long long* acc, const float* __restrict__ inp,
                              float* __restrict__ state, float* __restrict__ out, int t) {
    int stride = gridDim.x * blockDim.x;
    for (int i = blockIdx.x * blockDim.x + threadIdx.x; i < NB; i += stride) {
        int n = i >> 4, b = i & 15;
        float y = (float)((double)acc[i] * FXINV);
        acc[i] = 0LL;
        float v = activate(y);
        if (n < N_SENSORY) v += thresh_clamp_inp(inp[b * ST + n * T_LAYERS + (t + 1)]);
        v = fminf(v, 1.0f);
        state[i] = v;
        out[b * NT + n * T_LAYERS + t] = v;
    }
}
__global__ void k2_act_final(const long long* __restrict__ acc, float* __restrict__ out) {
    int stride = gridDim.x * blockDim.x;
    for (int i = blockIdx.x * blockDim.x + threadIdx.x; i < NB; i += stride) {
        int n = i >> 4, b = i & 15;
        float y = (float)((double)acc[i] * FXINV);
        out[b * NT + n * T_LAYERS + (T_LAYERS - 1)] = activate(y);
    }
}

extern "C" void kernel_launch(void* const* d_in, const int* in_sizes, int n_in,
                              void* d_out, int out_size, void* d_ws, size_t ws_size,
                              hipStream_t stream) {
    const float* inputs = (const float*)d_in[0];
    const float* vals   = (const float*)d_in[1];
    const int*   rows   = (const int*)  d_in[2];
    const int*   cols   = (const int*)  d_in[3];
    float* out = (float*)d_out;

    const size_t sz_planes = (size_t)T_LAYERS * NB * 4;   // 51.2 MB
    const size_t sz_packed = (size_t)NNZ_CNT * 8;         // 25.6 MB
    const size_t sz_rowptr = ((size_t)N_NEURONS + 2) * 4;
    const size_t sz_bt     = (size_t)(NBUCKET + 8) * 4;
    const size_t REQ = sz_planes + sz_packed + sz_rowptr + 2 * sz_bt;

    const int block = 256;

    if (ws_size >= REQ) {
        char* ws = (char*)d_ws;
        float* planes  = (float*)ws;                           // 8 planes of NB floats
        int2*  packed  = (int2*)(ws + sz_planes);              // persistent CSR payload
        int*   row_ptr = (int*)(ws + sz_planes + sz_packed);
        int*   btotal  = (int*)(ws + sz_planes + sz_packed + sz_rowptr);
        int*   bbase   = (int*)(ws + sz_planes + sz_packed + sz_rowptr + sz_bt);
        // build-time scratch aliases planes[0..6] (all dead before layer kernels run):
        int2*  slab  = (int2*)planes;                          // 25.6 MB = planes[0..3]
        char*  p4    = ws + (size_t)4 * NB * 4;                // planes[4..6] = 19.2 MB
        int*   C2    = (int*)p4;                               // 13.65 MB
        int*   M     = (int*)(p4 + (size_t)NCHUNK_B * BROWS * 4);  // 4.9 MB
        float* state0 = planes + (size_t)(T_LAYERS - 1) * NB;  // planes[7]

        const int grid_nb = (NB + block - 1) / block;          // 6250

        k_countA<<<(NCHUNK_A + 3) / 4, 256, 0, stream>>>(rows, M);
        k_scanA<<<NBUCKET, 1024, 0, stream>>>(M, btotal);
        k_bscan<<<1, 256, 0, stream>>>(btotal, bbase, row_ptr);
        k_placeA<<<(NCHUNK_A + 3) / 4, 256, 0, stream>>>(rows, cols, vals, M, bbase, slab);
        k_countB<<<NCHUNK_B, 256, 0, stream>>>(bbase, slab, C2);
        k_scanB<<<NBUCKET, 512, 0, stream>>>(bbase, C2, row_ptr);
        k_placeB<<<(NCHUNK_B + 3) / 4, 256, 0, stream>>>(bbase, slab, C2, packed);
        k_init<<<grid_nb, block, 0, stream>>>(inputs, state0);

        for (int t = 0; t < T_LAYERS; ++t) {
            const float* sin_ = (t == 0) ? state0 : planes + (size_t)(t - 1) * NB;
            k_layer<<<grid_nb, block, 0, stream>>>(row_ptr, packed, sin_, inputs,
                                                   planes + (size_t)t * NB, t);
        }
        k_out<<<grid_nb, block, 0, stream>>>(planes, out);
    } else {
        long long* acc   = (long long*)d_ws;
        float*     state = (float*)(acc + NB);
        const int grid_ew = 2048, grid_sp = 2048;
        k2_init<<<grid_ew, block, 0, stream>>>(inputs, state, acc);
        for (int t = 0; t < T_LAYERS; ++t) {
            k2_spmm<<<grid_sp, block, 0, stream>>>(vals, rows, cols, state, acc);
            if (t < T_LAYERS - 1)
                k2_act_inject<<<grid_ew, block, 0, stream>>>(acc, inputs, state, out, t);
            else
                k2_act_final<<<grid_ew, block, 0, stream>>>(acc, out);
        }
    }
}